// Round 20
// baseline (103.642 us; speedup 1.0000x reference)
//
#include <hip/hip_runtime.h>
#include <math.h>

#define B_DIM  48
#define S_DIM  96
#define D_DIM  54
#define DENC   4
#define DVAR   8
#define NFLAT  (B_DIM * S_DIM)   // 4608

// One complex amplitude = one 32-bit reg: (x=re in lo16, y=im in hi16), f16.
typedef _Float16 h2 __attribute__((ext_vector_type(2)));

__device__ __forceinline__ int h2i(h2 v) { return __builtin_bit_cast(int, v); }
__device__ __forceinline__ h2  i2h(int v) { return __builtin_bit_cast(h2, v); }

// Forced packed-f16 math (VOP3P) — R13-validated.
__device__ __forceinline__ int pk_mul(int a, int b) {
    int d;
    asm("v_pk_mul_f16 %0, %1, %2" : "=v"(d) : "v"(a), "v"(b));
    return d;
}
__device__ __forceinline__ int pk_fma(int a, int b, int c) {
    int d;
    asm("v_pk_fma_f16 %0, %1, %2, %3" : "=v"(d) : "v"(a), "v"(b), "v"(c));
    return d;
}

// f16x2 dot product with f32 accumulate — R18-validated.
__device__ __forceinline__ float fdot2(h2 a, h2 b, float c) {
#if __has_builtin(__builtin_amdgcn_fdot2)
    return __builtin_amdgcn_fdot2(a, b, c, false);
#else
    return fmaf((float)a.x, (float)b.x, fmaf((float)a.y, (float)b.y, c));
#endif
}

// Lane-xor primitives. lm=16 now on VALU via permlane16_swap (R4-validated
// semantics: ret[0]=[r0,r0,r2,r2], ret[1]=[r1,r1,r3,r3]; want [r1,r0,r3,r2]).
// This moves ~96 ops/wave OFF the per-CU-shared DS pipe (the suspected bottleneck).
template<int LM>
__device__ __forceinline__ int lxi(int x, int lane) {
    if constexpr (LM == 1)       return __builtin_amdgcn_update_dpp(x, x, 0xB1, 0xF, 0xF, true);  // quad[1,0,3,2]
    else if constexpr (LM == 2)  return __builtin_amdgcn_update_dpp(x, x, 0x4E, 0xF, 0xF, true);  // quad[2,3,0,1]
    else if constexpr (LM == 4)  return __builtin_amdgcn_ds_swizzle(x, 0x101F);                   // xor4 (DS; no VALU form)
    else if constexpr (LM == 8)  return __builtin_amdgcn_update_dpp(x, x, 0x128, 0xF, 0xF, true); // ROW_ROR:8
    else if constexpr (LM == 16) {
#if __has_builtin(__builtin_amdgcn_permlane16_swap)
        auto r = __builtin_amdgcn_permlane16_swap(x, x, false, false);
        return (lane & 16) ? r[0] : r[1];
#else
        return __builtin_amdgcn_ds_swizzle(x, 0x401F);
#endif
    } else {
        auto r = __builtin_amdgcn_permlane32_swap(x, x, false, false);
        return (lane & 32) ? r[0] : r[1];
    }
}
template<int LM>
__device__ __forceinline__ float lx(float v, int lane) {
    return __int_as_float(lxi<LM>(__float_as_int(v), lane));
}

// Wave reduction. 32-level select-free (R19-validated): r[0]+r[1] = lo+hi everywhere.
__device__ __forceinline__ float wave_sum(float v, int lane) {
    {
        int x = __float_as_int(v);
        auto r = __builtin_amdgcn_permlane32_swap(x, x, false, false);
        v = __int_as_float(r[0]) + __int_as_float(r[1]);
    }
    v += lx<16>(v, lane);
    v += lx<8>(v, lane);
    v += lx<4>(v, lane);
    v += lx<2>(v, lane);
    v += lx<1>(v, lane);
    return v;
}

// State layout: amp index i (9 bits) -> lane = i>>3 (bits 8..3), reg r = i&7 (bits 2..0).
// Qubit j <-> state bit BJ = 8-j.

// halves-swap (y,x) <- (x,y): one v_alignbit
__device__ __forceinline__ int hswapi(int p) {
    return __builtin_amdgcn_alignbit(p, p, 16);
}

__device__ __forceinline__ h2 bp(int addr, h2 v) {
    return i2h(__builtin_amdgcn_ds_bpermute(addr, h2i(v)));
}

// Ring bperm addresses (R17-validated fold of the (0,8) xor32 stage), plus a32
// for xor32 exchanges routed through the DS pipe (R18-validated).
struct RingAddr { int aA, aB, aC, aD, a32; };
__device__ __forceinline__ RingAddr make_ring_addr(int lane) {
    const int gray   = (lane ^ (lane >> 1)) << 2;
    const int gray48 = gray ^ 192;          // gray(L^32) = gray(L)^48, word addr <<2
    const bool c0 = (lane & 1) != 0;
    RingAddr ra;
    ra.aA  = gray;
    ra.aB  = gray48;
    ra.aC  = c0 ? gray : gray48;
    ra.aD  = c0 ? gray48 : gray;
    ra.a32 = (lane ^ 32) << 2;
    return ra;
}

// CNOT ring (control j, target (j+1)%9) — R17/R18-validated form.
__device__ __forceinline__ void ring(h2 st[8], const RingAddr& ra, int lane) {
    st[0] = bp(ra.aD, st[0]);
    st[1] = bp(ra.aB, st[1]);
    st[2] = bp(ra.aC, st[2]);
    st[3] = bp(ra.aA, st[3]);
    st[4] = bp(ra.aC, st[4]);
    st[5] = bp(ra.aB, st[5]);
    st[6] = bp(ra.aD, st[6]);
    st[7] = bp(ra.aA, st[7]);
    // (3,2): ctrl lane bit0 (b3), tgt reg bit2
    {
        const bool c0 = (lane & 1) != 0;
#pragma unroll
        for (int r = 0; r < 4; ++r) {
            h2 a = st[r], b = st[r + 4];
            st[r]     = c0 ? b : a;
            st[r + 4] = c0 ? a : b;
        }
    }
    // (2,1): regs with bit2: r <-> r^2 (rename)
    { h2 t = st[4]; st[4] = st[6]; st[6] = t; }
    { h2 t = st[5]; st[5] = st[7]; st[7] = t; }
    // (1,0): regs with bit1: r <-> r^1 (rename)
    { h2 t = st[2]; st[2] = st[3]; st[3] = t; }
    { h2 t = st[6]; st[6] = st[7]; st[7] = t; }
}

// RY(theta): n0 = c*a0 - s*a1 ; n1 = s*a0 + c*a1.  BJ==8 exchange via DS pipe (R18).
template<int BJ>
__device__ __forceinline__ void rot_ry(h2 st[8], int c2i, int s2i, int lane, int a32) {
    if constexpr (BJ >= 3) {
        constexpr int lm = 1 << (BJ - 3);
        const int sg = (lane & lm) ? s2i : (s2i ^ 0x80008000);
#pragma unroll
        for (int r = 0; r < 8; ++r) {
            int p;
            if constexpr (BJ == 8) p = h2i(bp(a32, st[r]));
            else                   p = lxi<lm>(h2i(st[r]), lane);
            st[r] = i2h(pk_fma(p, sg, pk_mul(h2i(st[r]), c2i)));
        }
    } else {
        constexpr int M = 1 << BJ;
        const int ns2 = s2i ^ 0x80008000;
#pragma unroll
        for (int r = 0; r < 8; ++r) {
            if ((r & M) == 0) {
                int a = h2i(st[r]), b = h2i(st[r + M]);
                st[r]     = i2h(pk_fma(b, ns2, pk_mul(a, c2i)));
                st[r + M] = i2h(pk_fma(a, s2i, pk_mul(b, c2i)));
            }
        }
    }
}

// RX(theta): n = c*a + (s,-s)*hswap(partner) — R11-validated form.
template<int BJ>
__device__ __forceinline__ void rot_rx(h2 st[8], int c2i, int s2i, int lane, int a32) {
    const int sm = s2i ^ 0x80000000;   // (s, -s)
    if constexpr (BJ >= 3) {
        constexpr int lm = 1 << (BJ - 3);
#pragma unroll
        for (int r = 0; r < 8; ++r) {
            int p;
            if constexpr (BJ == 8) p = h2i(bp(a32, st[r]));
            else                   p = lxi<lm>(h2i(st[r]), lane);
            st[r] = i2h(pk_fma(hswapi(p), sm, pk_mul(h2i(st[r]), c2i)));
        }
    } else {
        constexpr int M = 1 << BJ;
#pragma unroll
        for (int r = 0; r < 8; ++r) {
            if ((r & M) == 0) {
                int a = h2i(st[r]), b = h2i(st[r + M]);
                st[r]     = i2h(pk_fma(hswapi(b), sm, pk_mul(a, c2i)));
                st[r + M] = i2h(pk_fma(hswapi(a), sm, pk_mul(b, c2i)));
            }
        }
    }
}

#define INITQ(j) { rot_rx<8 - (j)>(st, cc[2 * (j)],     ss[2 * (j)],     lane, ra.a32);  \
                   rot_ry<8 - (j)>(st, cc[2 * (j) + 1], ss[2 * (j) + 1], lane, ra.a32); }

__device__ __forceinline__ void ry_layer(h2 st[8], const int* pc, const int* ps, int lane, int a32) {
    rot_ry<8>(st, pc[0], ps[0], lane, a32);
    rot_ry<7>(st, pc[1], ps[1], lane, a32);
    rot_ry<6>(st, pc[2], ps[2], lane, a32);
    rot_ry<5>(st, pc[3], ps[3], lane, a32);
    rot_ry<4>(st, pc[4], ps[4], lane, a32);
    rot_ry<3>(st, pc[5], ps[5], lane, a32);
    rot_ry<2>(st, pc[6], ps[6], lane, a32);
    rot_ry<1>(st, pc[7], ps[7], lane, a32);
    rot_ry<0>(st, pc[8], ps[8], lane, a32);
}

// <Z>, <X>, <Y> on qubit with state-bit BJ — dot2-based, f32 accumulation (R18).
template<int BJ>
__device__ __forceinline__ void expv(const h2 st[8], int lane, int a32,
                                     float& ez, float& ex, float& ey) {
    float pz = 0.f, pxa = 0.f, pya = 0.f;
    if constexpr (BJ >= 3) {
        constexpr int lm = 1 << (BJ - 3);
        const float sgn = (lane & lm) ? -1.f : 1.f;
#pragma unroll
        for (int r = 0; r < 8; ++r) {
            h2 a = st[r];
            h2 p;
            if constexpr (BJ == 8) p = bp(a32, a);
            else                   p = i2h(lxi<lm>(h2i(a), lane));
            pz  = fdot2(a, a, pz);
            pxa = fdot2(a, p, pxa);
            h2 pr = i2h(hswapi(h2i(p)) ^ 0x80000000);  // (p.y, -p.x)
            pya = fdot2(a, pr, pya);
        }
        ez = sgn * pz; ex = pxa; ey = sgn * pya;
    } else {
        constexpr int M = 1 << BJ;
        float nz = 0.f;
#pragma unroll
        for (int r = 0; r < 8; ++r) {
            if ((r & M) == 0) {
                h2 a = st[r], b = st[r + M];
                pz  = fdot2(a, a, pz);
                nz  = fdot2(b, b, nz);
                pxa = fdot2(a, b, pxa);
                h2 br = i2h(hswapi(h2i(b)) ^ 0x80000000);
                pya = fdot2(a, br, pya);
            }
        }
        ez = pz - nz; ex = 2.f * pxa; ey = 2.f * pya;
    }
    ez = wave_sum(ez, lane); ex = wave_sum(ex, lane); ey = wave_sum(ey, lane);
}

// ---- Phase A: encoding + checkpoint; weight tables fused (blocks 0-4). ----
__global__ __launch_bounds__(64) void enc_kernel(
    const float* __restrict__ inp,
    const float* __restrict__ wq, const float* __restrict__ wk, const float* __restrict__ wv,
    int* __restrict__ encOut, int* __restrict__ wcc, int* __restrict__ wss)
{
    __shared__ int csc[54];
    __shared__ int css[54];

    const int lane = threadIdx.x;
    const int fi   = blockIdx.x;     // flat = s*B + b
    const int b = fi % B_DIM, s = fi / B_DIM;
    const float* x = inp + ((size_t)b * S_DIM + s) * D_DIM;

    if (fi < 5 && lane < 54) {
        int k = fi * 54 + lane;
        const float* p = (k < 90) ? wq : (k < 180) ? wk : wv;
        float ang = p[k % 90];
        float sn, cn; sincosf(0.5f * ang, &sn, &cn);
        _Float16 hc = (_Float16)cn, hs = (_Float16)sn;
        h2 c2 = {hc, hc}, s2 = {hs, hs};
        wcc[k] = h2i(c2);
        wss[k] = h2i(s2);
    }

    if (lane < 54) {
        float ang = x[lane];
        float sn, cn; sincosf(0.5f * ang, &sn, &cn);
        _Float16 hc = (_Float16)cn, hs = (_Float16)sn;
        h2 c2 = {hc, hc}, s2 = {hs, hs};
        csc[lane] = h2i(c2);
        css[lane] = h2i(s2);
    }

    const RingAddr ra = make_ring_addr(lane);

    h2 st[8];
#pragma unroll
    for (int r = 0; r < 8; ++r) st[r] = i2h(0);
    if (lane == 0) { h2 one = {(_Float16)1.f, (_Float16)0.f}; st[0] = one; }

    {
        const int* cc = csc; const int* ss = css;
        INITQ(0) INITQ(1) INITQ(2) INITQ(3) INITQ(4)
        INITQ(5) INITQ(6) INITQ(7) INITQ(8)
        const int* pc = csc + 18;
        const int* ps = css + 18;
#pragma unroll 1
        for (int L = 0; L < DENC; ++L) {
            ring(st, ra, lane);
            ry_layer(st, pc, ps, lane, ra.a32);
            pc += 9; ps += 9;
        }
    }

    int* dst = encOut + (size_t)fi * 512;
#pragma unroll
    for (int r = 0; r < 8; ++r)
        dst[r * 64 + lane] = h2i(st[r]);
}

// ---- Phase B: one wave per (input, head). cid 0=Q 1=K 2=V. ----
__global__ __launch_bounds__(64) void var_kernel(
    const int* __restrict__ encIn,
    const int* __restrict__ wcc, const int* __restrict__ wss,
    float* __restrict__ outQ, float* __restrict__ outK, float* __restrict__ outV)
{
    __shared__ int csc[90];
    __shared__ int css[90];

    const int lane = threadIdx.x;
    const int gbl  = blockIdx.x;
    const int cid  = gbl % 3;            // 0=Q 1=K 2=V
    const int fi   = gbl / 3;            // flat = s*B + b

    for (int k = lane; k < 90; k += 64) {
        csc[k] = wcc[cid * 90 + k];
        css[k] = wss[cid * 90 + k];
    }

    const RingAddr ra = make_ring_addr(lane);

    // Load encoding checkpoint (coalesced).
    h2 st[8];
    const int* src = encIn + (size_t)fi * 512;
#pragma unroll
    for (int r = 0; r < 8; ++r)
        st[r] = i2h(src[r * 64 + lane]);

    // Variational circuit: init + (DVAR-1) full layers + final layer.
    {
        const int* cc = csc; const int* ss = css;
        INITQ(0) INITQ(1) INITQ(2) INITQ(3) INITQ(4)
        INITQ(5) INITQ(6) INITQ(7) INITQ(8)
        const int* pc = csc + 18;
        const int* ps = css + 18;
#pragma unroll 1
        for (int L = 0; L < DVAR - 1; ++L) {
            ring(st, ra, lane);
            ry_layer(st, pc, ps, lane, ra.a32);
            pc += 9; ps += 9;
        }
        ring(st, ra, lane);
        if (cid < 2) {
            // Final-layer RYs on qubits 1-8 commute with Z0 — exact trim.
            rot_ry<8>(st, pc[0], ps[0], lane, ra.a32);
        } else {
            ry_layer(st, pc, ps, lane, ra.a32);
        }
    }

    if (cid < 2) {
        float p = 0.f;
#pragma unroll
        for (int r = 0; r < 8; ++r)
            p = fdot2(st[r], st[r], p);
        p = (lane & 32) ? -p : p;     // qubit 0 = state bit 8 = lane bit 5
        p = wave_sum(p, lane);
        if (lane == 0) { if (cid == 0) outQ[fi] = p; else outK[fi] = p; }
    } else {
        float* vrow = outV + (size_t)fi * D_DIM;
#define EXPQ(q) { float ez, ex, ey; expv<8 - (q)>(st, lane, ra.a32, ez, ex, ey);    \
                  if (lane == 0) { vrow[(q)] = ez; vrow[9 + (q)] = ex;              \
                                   vrow[18 + (q)] = ey; vrow[27 + (q)] = ez;        \
                                   vrow[36 + (q)] = ex; vrow[45 + (q)] = ey; } }
        EXPQ(0) EXPQ(1) EXPQ(2) EXPQ(3) EXPQ(4)
        EXPQ(5) EXPQ(6) EXPQ(7) EXPQ(8)
#undef EXPQ
    }
}

__global__ __launch_bounds__(256) void attn_kernel(
    const float* __restrict__ inp, const float* __restrict__ Q,
    const float* __restrict__ K,   const float* __restrict__ V,
    float* __restrict__ out)
{
    __shared__ float w4[4][S_DIM];
    const int warp = threadIdx.x >> 6;
    const int t    = threadIdx.x & 63;
    const int bi   = blockIdx.x * 4 + warp;   // b*S + i
    const int b    = bi / S_DIM;
    const int i    = bi % S_DIM;
    float* w = w4[warp];

    const float q = Q[i * B_DIM + b];
    float e0, e1 = 0.f;
    {
        float d0 = q - K[t * B_DIM + b];
        e0 = expf(-d0 * d0);
        w[t] = e0;
        if (t < S_DIM - 64) {
            float d1 = q - K[(t + 64) * B_DIM + b];
            e1 = expf(-d1 * d1);
            w[t + 64] = e1;
        }
    }
    float ps = wave_sum(e0 + e1, t);
    const float inv = 1.f / ps;

    if (t < D_DIM) {
        float acc = 0.f;
        for (int j = 0; j < S_DIM; ++j)
            acc += w[j] * V[(size_t)(j * B_DIM + b) * D_DIM + t];
        size_t o = (size_t)bi * D_DIM + t;
        out[o] = inp[o] + acc * inv;
    }
}

extern "C" void kernel_launch(void* const* d_in, const int* in_sizes, int n_in,
                              void* d_out, int out_size, void* d_ws, size_t ws_size,
                              hipStream_t stream)
{
    (void)in_sizes; (void)n_in; (void)out_size; (void)ws_size;
    const float* inp = (const float*)d_in[0];
    const float* wq  = (const float*)d_in[1];
    const float* wk  = (const float*)d_in[2];
    const float* wv  = (const float*)d_in[3];
    float* outp = (float*)d_out;

    float* Qw  = (float*)d_ws;                           // 4608
    float* Kw  = Qw + NFLAT;                             // 4608
    float* Vw  = Kw + NFLAT;                             // 4608*54
    int*   Enc = (int*)(Vw + (size_t)NFLAT * D_DIM);     // 4608*512 ints (9.4 MB)
    int*   Wcc = Enc + (size_t)NFLAT * 512;              // 270
    int*   Wss = Wcc + 270;                              // 270

    enc_kernel<<<NFLAT, 64, 0, stream>>>(inp, wq, wk, wv, Enc, Wcc, Wss);
    var_kernel<<<NFLAT * 3, 64, 0, stream>>>(Enc, Wcc, Wss, Qw, Kw, Vw);
    attn_kernel<<<NFLAT / 4, 256, 0, stream>>>(inp, Qw, Kw, Vw, outp);
}

// Round 21
// 94.196 us; speedup vs baseline: 1.1003x; 1.1003x over previous
//
#include <hip/hip_runtime.h>
#include <math.h>

#define B_DIM  48
#define S_DIM  96
#define D_DIM  54
#define DENC   4
#define DVAR   8
#define NFLAT  (B_DIM * S_DIM)   // 4608

// One complex amplitude = one 32-bit reg: (x=re in lo16, y=im in hi16), f16.
typedef _Float16 h2 __attribute__((ext_vector_type(2)));

__device__ __forceinline__ int h2i(h2 v) { return __builtin_bit_cast(int, v); }
__device__ __forceinline__ h2  i2h(int v) { return __builtin_bit_cast(h2, v); }

// Forced packed-f16 math (VOP3P) — R13-validated.
__device__ __forceinline__ int pk_mul(int a, int b) {
    int d;
    asm("v_pk_mul_f16 %0, %1, %2" : "=v"(d) : "v"(a), "v"(b));
    return d;
}
__device__ __forceinline__ int pk_fma(int a, int b, int c) {
    int d;
    asm("v_pk_fma_f16 %0, %1, %2, %3" : "=v"(d) : "v"(a), "v"(b), "v"(c));
    return d;
}

// f16x2 dot product with f32 accumulate — R18-validated.
__device__ __forceinline__ float fdot2(h2 a, h2 b, float c) {
#if __has_builtin(__builtin_amdgcn_fdot2)
    return __builtin_amdgcn_fdot2(a, b, c, false);
#else
    return fmaf((float)a.x, (float)b.x, fmaf((float)a.y, (float)b.y, c));
#endif
}

// Lane-xor primitives — R19-exact set (lm=16 on DS: R20 proved VALU variant regresses).
template<int LM>
__device__ __forceinline__ int lxi(int x, int lane) {
    if constexpr (LM == 1)       return __builtin_amdgcn_update_dpp(x, x, 0xB1, 0xF, 0xF, true);  // quad[1,0,3,2]
    else if constexpr (LM == 2)  return __builtin_amdgcn_update_dpp(x, x, 0x4E, 0xF, 0xF, true);  // quad[2,3,0,1]
    else if constexpr (LM == 4)  return __builtin_amdgcn_ds_swizzle(x, 0x101F);                   // xor4
    else if constexpr (LM == 8)  return __builtin_amdgcn_update_dpp(x, x, 0x128, 0xF, 0xF, true); // ROW_ROR:8
    else if constexpr (LM == 16) return __builtin_amdgcn_ds_swizzle(x, 0x401F);                   // xor16
    else {
        auto r = __builtin_amdgcn_permlane32_swap(x, x, false, false);
        return (lane & 32) ? r[0] : r[1];
    }
}
template<int LM>
__device__ __forceinline__ float lx(float v, int lane) {
    return __int_as_float(lxi<LM>(__float_as_int(v), lane));
}

// Wave reduction. 32-level select-free (R19-validated): r[0]+r[1] = lo+hi everywhere.
__device__ __forceinline__ float wave_sum(float v, int lane) {
    {
        int x = __float_as_int(v);
        auto r = __builtin_amdgcn_permlane32_swap(x, x, false, false);
        v = __int_as_float(r[0]) + __int_as_float(r[1]);
    }
    v += lx<16>(v, lane);
    v += lx<8>(v, lane);
    v += lx<4>(v, lane);
    v += lx<2>(v, lane);
    v += lx<1>(v, lane);
    return v;
}

// State layout: amp index i (9 bits) -> lane = i>>3 (bits 8..3), reg r = i&7 (bits 2..0).
// Qubit j <-> state bit BJ = 8-j.

// halves-swap (y,x) <- (x,y): one v_alignbit
__device__ __forceinline__ int hswapi(int p) {
    return __builtin_amdgcn_alignbit(p, p, 16);
}

__device__ __forceinline__ h2 bp(int addr, h2 v) {
    return i2h(__builtin_amdgcn_ds_bpermute(addr, h2i(v)));
}

// Ring bperm addresses (R17-validated fold of the (0,8) xor32 stage), plus a32
// for xor32 exchanges routed through the DS pipe (R18-validated).
struct RingAddr { int aA, aB, aC, aD, a32; };
__device__ __forceinline__ RingAddr make_ring_addr(int lane) {
    const int gray   = (lane ^ (lane >> 1)) << 2;
    const int gray48 = gray ^ 192;          // gray(L^32) = gray(L)^48, word addr <<2
    const bool c0 = (lane & 1) != 0;
    RingAddr ra;
    ra.aA  = gray;
    ra.aB  = gray48;
    ra.aC  = c0 ? gray : gray48;
    ra.aD  = c0 ? gray48 : gray;
    ra.a32 = (lane ^ 32) << 2;
    return ra;
}

// CNOT ring (control j, target (j+1)%9) — R17/R18-validated form.
__device__ __forceinline__ void ring(h2 st[8], const RingAddr& ra, int lane) {
    st[0] = bp(ra.aD, st[0]);
    st[1] = bp(ra.aB, st[1]);
    st[2] = bp(ra.aC, st[2]);
    st[3] = bp(ra.aA, st[3]);
    st[4] = bp(ra.aC, st[4]);
    st[5] = bp(ra.aB, st[5]);
    st[6] = bp(ra.aD, st[6]);
    st[7] = bp(ra.aA, st[7]);
    // (3,2): ctrl lane bit0 (b3), tgt reg bit2
    {
        const bool c0 = (lane & 1) != 0;
#pragma unroll
        for (int r = 0; r < 4; ++r) {
            h2 a = st[r], b = st[r + 4];
            st[r]     = c0 ? b : a;
            st[r + 4] = c0 ? a : b;
        }
    }
    // (2,1): regs with bit2: r <-> r^2 (rename)
    { h2 t = st[4]; st[4] = st[6]; st[6] = t; }
    { h2 t = st[5]; st[5] = st[7]; st[7] = t; }
    // (1,0): regs with bit1: r <-> r^1 (rename)
    { h2 t = st[2]; st[2] = st[3]; st[3] = t; }
    { h2 t = st[6]; st[6] = st[7]; st[7] = t; }
}

// RY(theta): n0 = c*a0 - s*a1 ; n1 = s*a0 + c*a1.  BJ==8 exchange via DS pipe (R18).
template<int BJ>
__device__ __forceinline__ void rot_ry(h2 st[8], int c2i, int s2i, int lane, int a32) {
    if constexpr (BJ >= 3) {
        constexpr int lm = 1 << (BJ - 3);
        const int sg = (lane & lm) ? s2i : (s2i ^ 0x80008000);
#pragma unroll
        for (int r = 0; r < 8; ++r) {
            int p;
            if constexpr (BJ == 8) p = h2i(bp(a32, st[r]));
            else                   p = lxi<lm>(h2i(st[r]), lane);
            st[r] = i2h(pk_fma(p, sg, pk_mul(h2i(st[r]), c2i)));
        }
    } else {
        constexpr int M = 1 << BJ;
        const int ns2 = s2i ^ 0x80008000;
#pragma unroll
        for (int r = 0; r < 8; ++r) {
            if ((r & M) == 0) {
                int a = h2i(st[r]), b = h2i(st[r + M]);
                st[r]     = i2h(pk_fma(b, ns2, pk_mul(a, c2i)));
                st[r + M] = i2h(pk_fma(a, s2i, pk_mul(b, c2i)));
            }
        }
    }
}

// RX(theta): n = c*a + (s,-s)*hswap(partner) — R11-validated form.
template<int BJ>
__device__ __forceinline__ void rot_rx(h2 st[8], int c2i, int s2i, int lane, int a32) {
    const int sm = s2i ^ 0x80000000;   // (s, -s)
    if constexpr (BJ >= 3) {
        constexpr int lm = 1 << (BJ - 3);
#pragma unroll
        for (int r = 0; r < 8; ++r) {
            int p;
            if constexpr (BJ == 8) p = h2i(bp(a32, st[r]));
            else                   p = lxi<lm>(h2i(st[r]), lane);
            st[r] = i2h(pk_fma(hswapi(p), sm, pk_mul(h2i(st[r]), c2i)));
        }
    } else {
        constexpr int M = 1 << BJ;
#pragma unroll
        for (int r = 0; r < 8; ++r) {
            if ((r & M) == 0) {
                int a = h2i(st[r]), b = h2i(st[r + M]);
                st[r]     = i2h(pk_fma(hswapi(b), sm, pk_mul(a, c2i)));
                st[r + M] = i2h(pk_fma(hswapi(a), sm, pk_mul(b, c2i)));
            }
        }
    }
}

#define INITQ(j) { rot_rx<8 - (j)>(st, cc[2 * (j)],     ss[2 * (j)],     lane, ra.a32);  \
                   rot_ry<8 - (j)>(st, cc[2 * (j) + 1], ss[2 * (j) + 1], lane, ra.a32); }

__device__ __forceinline__ void ry_layer(h2 st[8], const int* pc, const int* ps, int lane, int a32) {
    rot_ry<8>(st, pc[0], ps[0], lane, a32);
    rot_ry<7>(st, pc[1], ps[1], lane, a32);
    rot_ry<6>(st, pc[2], ps[2], lane, a32);
    rot_ry<5>(st, pc[3], ps[3], lane, a32);
    rot_ry<4>(st, pc[4], ps[4], lane, a32);
    rot_ry<3>(st, pc[5], ps[5], lane, a32);
    rot_ry<2>(st, pc[6], ps[6], lane, a32);
    rot_ry<1>(st, pc[7], ps[7], lane, a32);
    rot_ry<0>(st, pc[8], ps[8], lane, a32);
}

// <Z>, <X>, <Y> on qubit with state-bit BJ — dot2-based, f32 accumulation (R18).
template<int BJ>
__device__ __forceinline__ void expv(const h2 st[8], int lane, int a32,
                                     float& ez, float& ex, float& ey) {
    float pz = 0.f, pxa = 0.f, pya = 0.f;
    if constexpr (BJ >= 3) {
        constexpr int lm = 1 << (BJ - 3);
        const float sgn = (lane & lm) ? -1.f : 1.f;
#pragma unroll
        for (int r = 0; r < 8; ++r) {
            h2 a = st[r];
            h2 p;
            if constexpr (BJ == 8) p = bp(a32, a);
            else                   p = i2h(lxi<lm>(h2i(a), lane));
            pz  = fdot2(a, a, pz);
            pxa = fdot2(a, p, pxa);
            h2 pr = i2h(hswapi(h2i(p)) ^ 0x80000000);  // (p.y, -p.x)
            pya = fdot2(a, pr, pya);
        }
        ez = sgn * pz; ex = pxa; ey = sgn * pya;
    } else {
        constexpr int M = 1 << BJ;
        float nz = 0.f;
#pragma unroll
        for (int r = 0; r < 8; ++r) {
            if ((r & M) == 0) {
                h2 a = st[r], b = st[r + M];
                pz  = fdot2(a, a, pz);
                nz  = fdot2(b, b, nz);
                pxa = fdot2(a, b, pxa);
                h2 br = i2h(hswapi(h2i(b)) ^ 0x80000000);
                pya = fdot2(a, br, pya);
            }
        }
        ez = pz - nz; ex = 2.f * pxa; ey = 2.f * pya;
    }
    ez = wave_sum(ez, lane); ex = wave_sum(ex, lane); ey = wave_sum(ey, lane);
}

// ---- Phase A: encoding + checkpoint; weight tables fused (blocks 0-4). ----
__global__ __launch_bounds__(64) void enc_kernel(
    const float* __restrict__ inp,
    const float* __restrict__ wq, const float* __restrict__ wk, const float* __restrict__ wv,
    int* __restrict__ encOut, int* __restrict__ wcc, int* __restrict__ wss)
{
    __shared__ int csc[54];
    __shared__ int css[54];

    const int lane = threadIdx.x;
    const int fi   = blockIdx.x;     // flat = s*B + b
    const int b = fi % B_DIM, s = fi / B_DIM;
    const float* x = inp + ((size_t)b * S_DIM + s) * D_DIM;

    if (fi < 5 && lane < 54) {
        int k = fi * 54 + lane;
        const float* p = (k < 90) ? wq : (k < 180) ? wk : wv;
        float ang = p[k % 90];
        float sn, cn; sincosf(0.5f * ang, &sn, &cn);
        _Float16 hc = (_Float16)cn, hs = (_Float16)sn;
        h2 c2 = {hc, hc}, s2 = {hs, hs};
        wcc[k] = h2i(c2);
        wss[k] = h2i(s2);
    }

    if (lane < 54) {
        float ang = x[lane];
        float sn, cn; sincosf(0.5f * ang, &sn, &cn);
        _Float16 hc = (_Float16)cn, hs = (_Float16)sn;
        h2 c2 = {hc, hc}, s2 = {hs, hs};
        csc[lane] = h2i(c2);
        css[lane] = h2i(s2);
    }

    const RingAddr ra = make_ring_addr(lane);

    h2 st[8];
#pragma unroll
    for (int r = 0; r < 8; ++r) st[r] = i2h(0);
    if (lane == 0) { h2 one = {(_Float16)1.f, (_Float16)0.f}; st[0] = one; }

    {
        const int* cc = csc; const int* ss = css;
        INITQ(0) INITQ(1) INITQ(2) INITQ(3) INITQ(4)
        INITQ(5) INITQ(6) INITQ(7) INITQ(8)
        const int* pc = csc + 18;
        const int* ps = css + 18;
#pragma unroll 1
        for (int L = 0; L < DENC; ++L) {
            ring(st, ra, lane);
            ry_layer(st, pc, ps, lane, ra.a32);
            pc += 9; ps += 9;
        }
    }

    int* dst = encOut + (size_t)fi * 512;
#pragma unroll
    for (int r = 0; r < 8; ++r)
        dst[r * 64 + lane] = h2i(st[r]);
}

// ---- Phase B: one wave per (input, head). cid 0=Q 1=K 2=V. ----
__global__ __launch_bounds__(64) void var_kernel(
    const int* __restrict__ encIn,
    const int* __restrict__ wcc, const int* __restrict__ wss,
    float* __restrict__ outQ, float* __restrict__ outK, float* __restrict__ outV)
{
    __shared__ int csc[90];
    __shared__ int css[90];

    const int lane = threadIdx.x;
    const int gbl  = blockIdx.x;
    const int cid  = gbl % 3;            // 0=Q 1=K 2=V
    const int fi   = gbl / 3;            // flat = s*B + b

    for (int k = lane; k < 90; k += 64) {
        csc[k] = wcc[cid * 90 + k];
        css[k] = wss[cid * 90 + k];
    }

    const RingAddr ra = make_ring_addr(lane);

    // Load encoding checkpoint (coalesced).
    h2 st[8];
    const int* src = encIn + (size_t)fi * 512;
#pragma unroll
    for (int r = 0; r < 8; ++r)
        st[r] = i2h(src[r * 64 + lane]);

    // Variational circuit: init + (DVAR-1) full layers + final layer.
    {
        const int* cc = csc; const int* ss = css;
        INITQ(0) INITQ(1) INITQ(2) INITQ(3) INITQ(4)
        INITQ(5) INITQ(6) INITQ(7) INITQ(8)
        const int* pc = csc + 18;
        const int* ps = css + 18;
#pragma unroll 1
        for (int L = 0; L < DVAR - 1; ++L) {
            ring(st, ra, lane);
            ry_layer(st, pc, ps, lane, ra.a32);
            pc += 9; ps += 9;
        }
        ring(st, ra, lane);
        if (cid < 2) {
            // Final-layer RYs on qubits 1-8 commute with Z0 — exact trim.
            rot_ry<8>(st, pc[0], ps[0], lane, ra.a32);
        } else {
            ry_layer(st, pc, ps, lane, ra.a32);
        }
    }

    if (cid < 2) {
        float p = 0.f;
#pragma unroll
        for (int r = 0; r < 8; ++r)
            p = fdot2(st[r], st[r], p);
        p = (lane & 32) ? -p : p;     // qubit 0 = state bit 8 = lane bit 5
        p = wave_sum(p, lane);
        if (lane == 0) { if (cid == 0) outQ[fi] = p; else outK[fi] = p; }
    } else {
        float* vrow = outV + (size_t)fi * D_DIM;
#define EXPQ(q) { float ez, ex, ey; expv<8 - (q)>(st, lane, ra.a32, ez, ex, ey);    \
                  if (lane == 0) { vrow[(q)] = ez; vrow[9 + (q)] = ex;              \
                                   vrow[18 + (q)] = ey; vrow[27 + (q)] = ez;        \
                                   vrow[36 + (q)] = ex; vrow[45 + (q)] = ey; } }
        EXPQ(0) EXPQ(1) EXPQ(2) EXPQ(3) EXPQ(4)
        EXPQ(5) EXPQ(6) EXPQ(7) EXPQ(8)
#undef EXPQ
    }
}

__global__ __launch_bounds__(256) void attn_kernel(
    const float* __restrict__ inp, const float* __restrict__ Q,
    const float* __restrict__ K,   const float* __restrict__ V,
    float* __restrict__ out)
{
    __shared__ float w4[4][S_DIM];
    const int warp = threadIdx.x >> 6;
    const int t    = threadIdx.x & 63;
    const int bi   = blockIdx.x * 4 + warp;   // b*S + i
    const int b    = bi / S_DIM;
    const int i    = bi % S_DIM;
    float* w = w4[warp];

    const float q = Q[i * B_DIM + b];
    float e0, e1 = 0.f;
    {
        float d0 = q - K[t * B_DIM + b];
        e0 = expf(-d0 * d0);
        w[t] = e0;
        if (t < S_DIM - 64) {
            float d1 = q - K[(t + 64) * B_DIM + b];
            e1 = expf(-d1 * d1);
            w[t + 64] = e1;
        }
    }
    float ps = wave_sum(e0 + e1, t);
    const float inv = 1.f / ps;

    if (t < D_DIM) {
        float acc = 0.f;
        for (int j = 0; j < S_DIM; ++j)
            acc += w[j] * V[(size_t)(j * B_DIM + b) * D_DIM + t];
        size_t o = (size_t)bi * D_DIM + t;
        out[o] = inp[o] + acc * inv;
    }
}

extern "C" void kernel_launch(void* const* d_in, const int* in_sizes, int n_in,
                              void* d_out, int out_size, void* d_ws, size_t ws_size,
                              hipStream_t stream)
{
    (void)in_sizes; (void)n_in; (void)out_size; (void)ws_size;
    const float* inp = (const float*)d_in[0];
    const float* wq  = (const float*)d_in[1];
    const float* wk  = (const float*)d_in[2];
    const float* wv  = (const float*)d_in[3];
    float* outp = (float*)d_out;

    float* Qw  = (float*)d_ws;                           // 4608
    float* Kw  = Qw + NFLAT;                             // 4608
    float* Vw  = Kw + NFLAT;                             // 4608*54
    int*   Enc = (int*)(Vw + (size_t)NFLAT * D_DIM);     // 4608*512 ints (9.4 MB)
    int*   Wcc = Enc + (size_t)NFLAT * 512;              // 270
    int*   Wss = Wcc + 270;                              // 270

    enc_kernel<<<NFLAT, 64, 0, stream>>>(inp, wq, wk, wv, Enc, Wcc, Wss);
    var_kernel<<<NFLAT * 3, 64, 0, stream>>>(Enc, Wcc, Wss, Qw, Kw, Vw);
    attn_kernel<<<NFLAT / 4, 256, 0, stream>>>(inp, Qw, Kw, Vw, outp);
}